// Round 24
// baseline (414.941 us; speedup 1.0000x reference)
//
#include <hip/hip_runtime.h>
#include <math.h>

#define T_LEN 32768
#define NB 4
#define NC 64
#define NL 18

typedef __attribute__((ext_vector_type(8))) short s16x8;
typedef __attribute__((ext_vector_type(4))) float f32x4;
#define MFMA_F16 __builtin_amdgcn_mfma_f32_16x16x32_f16

// raw barriers: never drain vmcnt mid-pipeline (T3/T4).
#define BAR_LGKM()                                                   \
    do {                                                             \
        asm volatile("s_waitcnt lgkmcnt(0)" ::: "memory");           \
        __builtin_amdgcn_s_barrier();                                \
        __builtin_amdgcn_sched_barrier(0);                           \
    } while (0)
#define BAR_VM(N)                                                    \
    do {                                                             \
        asm volatile("s_waitcnt vmcnt(%0) lgkmcnt(0)" ::             \
                         "i"(N) : "memory");                         \
        __builtin_amdgcn_s_barrier();                                \
        __builtin_amdgcn_sched_barrier(0);                           \
    } while (0)

__device__ inline unsigned short f2h(float f) {
    _Float16 h = (_Float16)f;       // RNE
    return __builtin_bit_cast(unsigned short, h);
}
__device__ inline unsigned pack_h2(float a, float b) {
    return (unsigned)f2h(a) | ((unsigned)f2h(b) << 16);
}
__device__ inline float h2f(unsigned short u) {
    return (float)__builtin_bit_cast(_Float16, u);
}
__device__ inline float fast_sigmoid(float x) {
    return __builtin_amdgcn_rcpf(1.f + __expf(-x));
}
__device__ inline float fast_tanh(float x) {
    return 1.f - 2.f * __builtin_amdgcn_rcpf(1.f + __expf(2.f * x));
}

// ------------------------------------------------------------------
// prep: weights -> fp16; out init = mix_b; zerobuf = 0
// ------------------------------------------------------------------
__global__ void prep_kernel(const float* __restrict__ hid_w,
                            const float* __restrict__ res_w,
                            const float* __restrict__ mix_b,
                            unsigned short* __restrict__ Wh,
                            unsigned short* __restrict__ Wr,
                            float* __restrict__ out,
                            float* __restrict__ zerobuf) {
    const int nW1 = NL * 128 * 192;        // 442368
    const int nW2 = NL * 64 * 64;          // 73728
    const int nOut = NB * T_LEN;           // 131072
    const int total = nW1 + nW2 + nOut + 48;
    for (int gid = blockIdx.x * blockDim.x + threadIdx.x; gid < total;
         gid += gridDim.x * blockDim.x) {
        if (gid < nW1) {
            int K = gid % 192;
            int co = (gid / 192) & 127;
            int i = gid / (192 * 128);
            int kt = K >> 6, ci = K & 63;
            Wh[gid] = f2h(hid_w[((i * 128 + co) * 64 + ci) * 3 + kt]);
        } else if (gid < nW1 + nW2) {
            int q = gid - nW1;
            int c = q & 63, co = (q >> 6) & 63, i = q >> 12;
            Wr[q] = f2h(res_w[(i * 64 + co) * 64 + c]);
        } else if (gid < nW1 + nW2 + nOut) {
            out[gid - (nW1 + nW2)] = mix_b[0];
        } else {
            zerobuf[gid - (nW1 + nW2 + nOut)] = 0.f;
        }
    }
}

// ------------------------------------------------------------------
// single fused layer (R23 kernel verbatim, 345us baseline)
// ------------------------------------------------------------------
template <int DIL, bool FIRST, bool LAST>
__launch_bounds__(256, 4)
__global__ void layer_kernel(const unsigned short* __restrict__ actH,
                             unsigned short* __restrict__ outH,
                             const unsigned short* __restrict__ Wh,
                             const float* __restrict__ hb,
                             const unsigned short* __restrict__ Wr,
                             const float* __restrict__ rb,
                             const float* __restrict__ mw,
                             float* __restrict__ skip,
                             const float* __restrict__ zerobuf,
                             const float* __restrict__ x,
                             const float* __restrict__ in_w,
                             const float* __restrict__ in_b) {
    constexpr bool UNI = (DIL < 64);
    constexpr int R = UNI ? (64 + 2 * DIL) : 192;
    constexpr int SLOTS = R * 8;
    constexpr int JMAX = (SLOTS + 255) / 256;
    constexpr int GS_BASE = (UNI ? 128 : 0) * 128;
    constexpr int OUT_BASE = (UNI ? 0 : 64) * 128;
    constexpr int REG = 24576;

    __shared__ uint4 Xs[2 * 1536];
    __shared__ float Sk[256];
    char* lds = (char*)Xs;

    const int tid = threadIdx.x;
    const int w = tid >> 6;
    const int l = tid & 63;
    const int lo = l & 15;
    const int hi = l >> 4;
    const int blk = blockIdx.x;
    const int tile = (blk & 7) * 64 + (blk >> 3);
    const int t0 = tile * 64;
    const int m0 = 16 * w;
    const int c0 = m0 + 4 * hi;

    const float* xB0 = x;

    s16x8 AH[2][6];
    s16x8 AR[2];
#pragma unroll
    for (int mt = 0; mt < 2; mt++) {
        const unsigned short* wp = Wh + (size_t)(m0 + 64 * mt + lo) * 192;
#pragma unroll
        for (int s = 0; s < 6; s++)
            AH[mt][s] = *(const s16x8*)(wp + 32 * s + 8 * hi);
    }
    if (!LAST) {
#pragma unroll
        for (int s = 0; s < 2; s++)
            AR[s] = *(const s16x8*)(Wr + (size_t)(m0 + lo) * 64 + 32 * s + 8 * hi);
    }
    float bA[4], bB[4], rbv[4];
#pragma unroll
    for (int r = 0; r < 4; r++) {
        bA[r] = hb[c0 + r];
        bB[r] = hb[64 + c0 + r];
        rbv[r] = LAST ? 0.f : rb[c0 + r];
    }
    const float4 mw4 = *(const float4*)(mw + c0);

    auto stage_async = [&](int bb, char* X) {
        const unsigned short* aB = actH + (size_t)bb * T_LEN * NC;
#pragma unroll
        for (int jj = 0; jj < JMAX; jj++) {
            int s = (w * JMAX + jj) * 64 + l;
            const void* src;
            if (s >= SLOTS) {
                src = (const void*)(zerobuf + (s & 7) * 4);
            } else {
                int row = s >> 3, ch = s & 7;
                int chunk = ch ^ (row & 7);
                int tg = t0 + (UNI ? (row - 2 * DIL)
                                   : (((row >> 6) - 2) * DIL + (row & 63)));
                src = (tg >= 0)
                          ? (const void*)(aB + (size_t)tg * 64 + chunk * 8)
                          : (const void*)(zerobuf + chunk * 4);
            }
            __builtin_amdgcn_global_load_lds(
                (const __attribute__((address_space(1))) unsigned int*)src,
                (__attribute__((address_space(3))) unsigned int*)(X +
                                                        (w * JMAX + jj) * 1024),
                16, 0, 0);
        }
    };
    auto stage_first = [&](int bb, char* X) {
        const float* xB = xB0 + (size_t)bb * T_LEN;
#pragma unroll
        for (int jj = 0; jj < JMAX; jj++) {
            int p = jj * 256 + tid;
            if (p < SLOTS) {
                int row = p >> 3, ch = p & 7;
                int tg = t0 + row - 2 * DIL;
                unsigned uu[4] = {0u, 0u, 0u, 0u};
                if (tg >= 0) {
                    float a = xB[tg];
#pragma unroll
                    for (int e = 0; e < 4; e++) {
                        float v0 = a * in_w[ch * 8 + 2 * e] + in_b[ch * 8 + 2 * e];
                        float v1 = a * in_w[ch * 8 + 2 * e + 1] + in_b[ch * 8 + 2 * e + 1];
                        uu[e] = pack_h2(v0, v1);
                    }
                }
                int byte = (row * 128 + ch * 16) ^ ((row & 7) << 4);
                *(uint4*)(X + byte) = make_uint4(uu[0], uu[1], uu[2], uu[3]);
            }
        }
    };

    if (FIRST) stage_first(0, lds);
    else       stage_async(0, lds);

#pragma unroll
    for (int j = 0; j < NB; j++) {
        char* X = lds + (j & 1) * REG;
        const int b = j;

        if (j + 1 < NB) {
            if (FIRST) stage_first(j + 1, lds + ((j + 1) & 1) * REG);
            else       stage_async(j + 1, lds + ((j + 1) & 1) * REG);
        }

        if (FIRST)           { BAR_LGKM(); }
        else if (j + 1 < NB) { BAR_VM(JMAX); }
        else                 { BAR_VM(0); }

        f32x4 acc[2][4];
#pragma unroll
        for (int mt = 0; mt < 2; mt++)
#pragma unroll
            for (int nt = 0; nt < 4; nt++)
                acc[mt][nt] = (f32x4){0.f, 0.f, 0.f, 0.f};
        __builtin_amdgcn_s_setprio(1);
#pragma unroll
        for (int s = 0; s < 6; s++) {
            const int tap = s >> 1, half = s & 1;
#pragma unroll
            for (int nt = 0; nt < 4; nt++) {
                int t = 16 * nt + lo;
                int row = UNI ? (t + tap * DIL) : (tap * 64 + t);
                int byte = (row * 128 + half * 64 + hi * 16) ^ ((row & 7) << 4);
                s16x8 bx = __builtin_bit_cast(s16x8, *(const uint4*)(X + byte));
                acc[0][nt] = MFMA_F16(AH[0][s], bx, acc[0][nt], 0, 0, 0);
                acc[1][nt] = MFMA_F16(AH[1][s], bx, acc[1][nt], 0, 0, 0);
            }
        }
        __builtin_amdgcn_s_setprio(0);

        float4 inp[4];
        if (!LAST) {
#pragma unroll
            for (int nt = 0; nt < 4; nt++) {
                int t = 16 * nt + lo;
                int rowI = UNI ? (t + 2 * DIL) : (128 + t);
                int byteI = (rowI * 128 + c0 * 2) ^ ((rowI & 7) << 4);
                uint2 hv = *(const uint2*)(X + byteI);
                inp[nt] = make_float4(h2f((unsigned short)(hv.x & 0xffff)),
                                      h2f((unsigned short)(hv.x >> 16)),
                                      h2f((unsigned short)(hv.y & 0xffff)),
                                      h2f((unsigned short)(hv.y >> 16)));
            }
        }

        BAR_LGKM();

#pragma unroll
        for (int nt = 0; nt < 4; nt++) {
            float g[4];
#pragma unroll
            for (int r = 0; r < 4; r++) {
                float hA = acc[0][nt][r] + bA[r];
                float hB = acc[1][nt][r] + bB[r];
                g[r] = fast_tanh(hA) * fast_sigmoid(hB);
            }
            int t = 16 * nt + lo;
            if (!LAST) {
                int byte = (t * 128 + c0 * 2) ^ ((t & 7) << 4);
                *(uint2*)(X + GS_BASE + byte) =
                    make_uint2(pack_h2(g[0], g[1]), pack_h2(g[2], g[3]));
            }
            float sk = g[0] * mw4.x + g[1] * mw4.y + g[2] * mw4.z + g[3] * mw4.w;
            sk += __shfl_xor(sk, 16, 64);
            sk += __shfl_xor(sk, 32, 64);
            if (hi == 0) Sk[w * 64 + nt * 16 + lo] = sk;
        }
        BAR_LGKM();

        if (LAST) {
            if (tid < 64) {
                float s2 = Sk[tid] + Sk[64 + tid] + Sk[128 + tid] + Sk[192 + tid];
                skip[(size_t)b * T_LEN + t0 + tid] += s2;
            }
            BAR_LGKM();
            continue;
        }

        f32x4 acc2[4];
#pragma unroll
        for (int nt = 0; nt < 4; nt++) acc2[nt] = (f32x4){0.f, 0.f, 0.f, 0.f};
        __builtin_amdgcn_s_setprio(1);
#pragma unroll
        for (int s = 0; s < 2; s++) {
#pragma unroll
            for (int nt = 0; nt < 4; nt++) {
                int t = 16 * nt + lo;
                int byte = (t * 128 + s * 64 + hi * 16) ^ ((t & 7) << 4);
                s16x8 bg = __builtin_bit_cast(
                    s16x8, *(const uint4*)(X + GS_BASE + byte));
                acc2[nt] = MFMA_F16(AR[s], bg, acc2[nt], 0, 0, 0);
            }
        }
        __builtin_amdgcn_s_setprio(0);

        char* OutH = X + OUT_BASE;
#pragma unroll
        for (int nt = 0; nt < 4; nt++) {
            int t = 16 * nt + lo;
            float ox = acc2[nt][0] + rbv[0] + inp[nt].x;
            float oy = acc2[nt][1] + rbv[1] + inp[nt].y;
            float oz = acc2[nt][2] + rbv[2] + inp[nt].z;
            float ow = acc2[nt][3] + rbv[3] + inp[nt].w;
            int byteB = (t * 128 + c0 * 2) ^ ((t & 7) << 4);
            *(uint2*)(OutH + byteB) =
                make_uint2(pack_h2(ox, oy), pack_h2(oz, ow));
        }

        if (tid < 64) {
            float s2 = Sk[tid] + Sk[64 + tid] + Sk[128 + tid] + Sk[192 + tid];
            skip[(size_t)b * T_LEN + t0 + tid] += s2;
        }
        BAR_LGKM();

        unsigned short* gH = outH + (size_t)b * T_LEN * NC + (size_t)t0 * 64;
#pragma unroll
        for (int i = 0; i < 2; i++) {
            int u = i * 256 + tid;
            int t = u >> 3, ch = u & 7;
            uint4 v = *(const uint4*)(OutH + t * 128 + ((ch ^ (t & 7)) << 4));
            ((uint4*)gH)[u] = v;
        }
        BAR_LGKM();
    }
}

// ------------------------------------------------------------------
// fused PAIR of layers (dilations DA then DB, both small: 2*DB <= 16).
// Layer A computed on an 80-pos extended window [t0-16, t0+64) (5 MFMA
// tiles); its activation stays in LDS (OutA) and feeds layer B's 64-pos
// tile. Removes 1 launch + 33MB global round-trip per pair.
// Overlays: GsA and OutB live in the current X half (writes are >=1
// barrier after the region's last read). OutA rows with t<0 are ZEROED
// (reference zero-pads B's conv input). 7 barriers/item.
// ------------------------------------------------------------------
template <int DA, int DB>
__launch_bounds__(256, 2)
__global__ void pair_kernel(const unsigned short* __restrict__ actH,
                            unsigned short* __restrict__ outH,
                            const unsigned short* __restrict__ WhA,
                            const float* __restrict__ hbA,
                            const unsigned short* __restrict__ WrA,
                            const float* __restrict__ rbA,
                            const float* __restrict__ mwA,
                            const unsigned short* __restrict__ WhB,
                            const float* __restrict__ hbB,
                            const unsigned short* __restrict__ WrB,
                            const float* __restrict__ rbB,
                            const float* __restrict__ mwB,
                            float* __restrict__ skip,
                            const float* __restrict__ zerobuf) {
    constexpr int R = 80 + 2 * DA;          // staged A-input rows
    constexpr int SLOTS = R * 8;
    constexpr int JMAX = (SLOTS + 255) / 256;
    constexpr int REG = 12288;              // 96-row X half

    __shared__ uint4 Xs[2 * 768];           // 24 KB double buffer
    __shared__ uint4 OutA[640];             // 80x128B = 10 KB (A act)
    __shared__ uint4 GsB[512];              // 64x128B = 8 KB
    __shared__ float Sk[256];
    char* lds = (char*)Xs;
    char* outa = (char*)OutA;
    char* gsb = (char*)GsB;

    const int tid = threadIdx.x;
    const int w = tid >> 6;
    const int l = tid & 63;
    const int lo = l & 15;
    const int hi = l >> 4;
    const int blk = blockIdx.x;
    const int tile = (blk & 7) * 64 + (blk >> 3);
    const int t0 = tile * 64;
    const int m0 = 16 * w;
    const int c0 = m0 + 4 * hi;

    // ---- W fragments + biases for both layers ----
    s16x8 AHa[2][6], ARa[2], AHb[2][6], ARb[2];
#pragma unroll
    for (int mt = 0; mt < 2; mt++) {
        const unsigned short* wa = WhA + (size_t)(m0 + 64 * mt + lo) * 192;
        const unsigned short* wb = WhB + (size_t)(m0 + 64 * mt + lo) * 192;
#pragma unroll
        for (int s = 0; s < 6; s++) {
            AHa[mt][s] = *(const s16x8*)(wa + 32 * s + 8 * hi);
            AHb[mt][s] = *(const s16x8*)(wb + 32 * s + 8 * hi);
        }
    }
#pragma unroll
    for (int s = 0; s < 2; s++) {
        ARa[s] = *(const s16x8*)(WrA + (size_t)(m0 + lo) * 64 + 32 * s + 8 * hi);
        ARb[s] = *(const s16x8*)(WrB + (size_t)(m0 + lo) * 64 + 32 * s + 8 * hi);
    }
    float bAa[4], bBa[4], rva[4], bAb[4], bBb[4], rvb[4];
#pragma unroll
    for (int r = 0; r < 4; r++) {
        bAa[r] = hbA[c0 + r];
        bBa[r] = hbA[64 + c0 + r];
        rva[r] = rbA[c0 + r];
        bAb[r] = hbB[c0 + r];
        bBb[r] = hbB[64 + c0 + r];
        rvb[r] = rbB[c0 + r];
    }
    const float4 mw4a = *(const float4*)(mwA + c0);
    const float4 mw4b = *(const float4*)(mwB + c0);

    auto stage = [&](int bb, char* X) {
        const unsigned short* aB = actH + (size_t)bb * T_LEN * NC;
#pragma unroll
        for (int jj = 0; jj < JMAX; jj++) {
            int s = (w * JMAX + jj) * 64 + l;
            const void* src;
            if (s >= SLOTS) {
                src = (const void*)(zerobuf + (s & 7) * 4);
            } else {
                int row = s >> 3, ch = s & 7;
                int chunk = ch ^ (row & 7);
                int tg = t0 - 16 - 2 * DA + row;
                src = (tg >= 0)
                          ? (const void*)(aB + (size_t)tg * 64 + chunk * 8)
                          : (const void*)(zerobuf + chunk * 4);
            }
            __builtin_amdgcn_global_load_lds(
                (const __attribute__((address_space(1))) unsigned int*)src,
                (__attribute__((address_space(3))) unsigned int*)(X +
                                                        (w * JMAX + jj) * 1024),
                16, 0, 0);
        }
    };

    stage(0, lds);

#pragma unroll
    for (int j = 0; j < NB; j++) {
        char* X = lds + (j & 1) * REG;
        const int b = j;

        if (j + 1 < NB) stage(j + 1, lds + ((j + 1) & 1) * REG);

        if (j + 1 < NB) { BAR_VM(JMAX); }
        else            { BAR_VM(0); }

        // ---- A hid GEMM on 80 positions (5 tiles); row = e + tap*DA ----
        f32x4 acc[2][5];
#pragma unroll
        for (int mt = 0; mt < 2; mt++)
#pragma unroll
            for (int nt = 0; nt < 5; nt++)
                acc[mt][nt] = (f32x4){0.f, 0.f, 0.f, 0.f};
        __builtin_amdgcn_s_setprio(1);
#pragma unroll
        for (int s = 0; s < 6; s++) {
            const int tap = s >> 1, half = s & 1;
#pragma unroll
            for (int nt = 0; nt < 5; nt++) {
                int e = 16 * nt + lo;
                int row = e + tap * DA;
                int byte = (row * 128 + half * 64 + hi * 16) ^ ((row & 7) << 4);
                s16x8 bx = __builtin_bit_cast(s16x8, *(const uint4*)(X + byte));
                acc[0][nt] = MFMA_F16(AHa[0][s], bx, acc[0][nt], 0, 0, 0);
                acc[1][nt] = MFMA_F16(AHa[1][s], bx, acc[1][nt], 0, 0, 0);
            }
        }
        __builtin_amdgcn_s_setprio(0);

        // ---- A residual input (X row e + 2*DA) ----
        float4 inpa[5];
#pragma unroll
        for (int nt = 0; nt < 5; nt++) {
            int e = 16 * nt + lo;
            int rowI = e + 2 * DA;
            int byteI = (rowI * 128 + c0 * 2) ^ ((rowI & 7) << 4);
            uint2 hv = *(const uint2*)(X + byteI);
            inpa[nt] = make_float4(h2f((unsigned short)(hv.x & 0xffff)),
                                   h2f((unsigned short)(hv.x >> 16)),
                                   h2f((unsigned short)(hv.y & 0xffff)),
                                   h2f((unsigned short)(hv.y >> 16)));
        }

        BAR_LGKM();   // X reads done -> GsA overlay (at X base) safe

        // ---- A gating -> GsA (overlay X[0..10K)) + A skip partials ----
#pragma unroll
        for (int nt = 0; nt < 5; nt++) {
            float g[4];
#pragma unroll
            for (int r = 0; r < 4; r++) {
                float hA = acc[0][nt][r] + bAa[r];
                float hB = acc[1][nt][r] + bBa[r];
                g[r] = fast_tanh(hA) * fast_sigmoid(hB);
            }
            int e = 16 * nt + lo;
            int byte = (e * 128 + c0 * 2) ^ ((e & 7) << 4);
            *(uint2*)(X + byte) =
                make_uint2(pack_h2(g[0], g[1]), pack_h2(g[2], g[3]));
            if (nt >= 1) {
                float sk = g[0] * mw4a.x + g[1] * mw4a.y + g[2] * mw4a.z +
                           g[3] * mw4a.w;
                sk += __shfl_xor(sk, 16, 64);
                sk += __shfl_xor(sk, 32, 64);
                if (hi == 0) Sk[w * 64 + (nt - 1) * 16 + lo] = sk;
            }
        }
        BAR_LGKM();   // GsA + SkA visible

        // ---- A res GEMM (reads GsA) ----
        f32x4 acc2[5];
#pragma unroll
        for (int nt = 0; nt < 5; nt++) acc2[nt] = (f32x4){0.f, 0.f, 0.f, 0.f};
        __builtin_amdgcn_s_setprio(1);
#pragma unroll
        for (int s = 0; s < 2; s++) {
#pragma unroll
            for (int nt = 0; nt < 5; nt++) {
                int e = 16 * nt + lo;
                int byte = (e * 128 + s * 64 + hi * 16) ^ ((e & 7) << 4);
                s16x8 bg = __builtin_bit_cast(s16x8, *(const uint4*)(X + byte));
                acc2[nt] = MFMA_F16(ARa[s], bg, acc2[nt], 0, 0, 0);
            }
        }
        __builtin_amdgcn_s_setprio(0);

        // ---- A act -> OutA (ZERO for t<0: reference zero-pads B input) ----
#pragma unroll
        for (int nt = 0; nt < 5; nt++) {
            int e = 16 * nt + lo;
            int tg_a = t0 - 16 + e;
            float ox = acc2[nt][0] + rva[0] + inpa[nt].x;
            float oy = acc2[nt][1] + rva[1] + inpa[nt].y;
            float oz = acc2[nt][2] + rva[2] + inpa[nt].z;
            float ow = acc2[nt][3] + rva[3] + inpa[nt].w;
            if (tg_a < 0) { ox = 0.f; oy = 0.f; oz = 0.f; ow = 0.f; }
            int byte = (e * 128 + c0 * 2) ^ ((e & 7) << 4);
            *(uint2*)(outa + byte) =
                make_uint2(pack_h2(ox, oy), pack_h2(oz, ow));
        }
        // ---- A skip global write ----
        if (tid < 64) {
            float s2 = Sk[tid] + Sk[64 + tid] + Sk[128 + tid] + Sk[192 + tid];
            skip[(size_t)b * T_LEN + t0 + tid] += s2;
        }
        BAR_LGKM();   // OutA visible; GsA + SkA dead

        // ---- B hid GEMM (reads OutA; row = u + 16 + (tap-2)*DB) ----
        f32x4 accb[2][4];
#pragma unroll
        for (int mt = 0; mt < 2; mt++)
#pragma unroll
            for (int nt = 0; nt < 4; nt++)
                accb[mt][nt] = (f32x4){0.f, 0.f, 0.f, 0.f};
        __builtin_amdgcn_s_setprio(1);
#pragma unroll
        for (int s = 0; s < 6; s++) {
            const int tap = s >> 1, half = s & 1;
#pragma unroll
            for (int nt = 0; nt < 4; nt++) {
                int u = 16 * nt + lo;
                int row = u + 16 + (tap - 2) * DB;
                int byte = (row * 128 + half * 64 + hi * 16) ^ ((row & 7) << 4);
                s16x8 bx =
                    __builtin_bit_cast(s16x8, *(const uint4*)(outa + byte));
                accb[0][nt] = MFMA_F16(AHb[0][s], bx, accb[0][nt], 0, 0, 0);
                accb[1][nt] = MFMA_F16(AHb[1][s], bx, accb[1][nt], 0, 0, 0);
            }
        }
        __builtin_amdgcn_s_setprio(0);

        // ---- B residual input (OutA row u+16) ----
        float4 inpb[4];
#pragma unroll
        for (int nt = 0; nt < 4; nt++) {
            int u = 16 * nt + lo;
            int rowI = u + 16;
            int byteI = (rowI * 128 + c0 * 2) ^ ((rowI & 7) << 4);
            uint2 hv = *(const uint2*)(outa + byteI);
            inpb[nt] = make_float4(h2f((unsigned short)(hv.x & 0xffff)),
                                   h2f((unsigned short)(hv.x >> 16)),
                                   h2f((unsigned short)(hv.y & 0xffff)),
                                   h2f((unsigned short)(hv.y >> 16)));
        }

        // ---- B gating -> GsB + B skip partials ----
#pragma unroll
        for (int nt = 0; nt < 4; nt++) {
            float g[4];
#pragma unroll
            for (int r = 0; r < 4; r++) {
                float hA = accb[0][nt][r] + bAb[r];
                float hB = accb[1][nt][r] + bBb[r];
                g[r] = fast_tanh(hA) * fast_sigmoid(hB);
            }
            int u = 16 * nt + lo;
            int byte = (u * 128 + c0 * 2) ^ ((u & 7) << 4);
            *(uint2*)(gsb + byte) =
                make_uint2(pack_h2(g[0], g[1]), pack_h2(g[2], g[3]));
            float sk = g[0] * mw4b.x + g[1] * mw4b.y + g[2] * mw4b.z +
                       g[3] * mw4b.w;
            sk += __shfl_xor(sk, 16, 64);
            sk += __shfl_xor(sk, 32, 64);
            if (hi == 0) Sk[w * 64 + nt * 16 + lo] = sk;
        }
        BAR_LGKM();   // GsB + SkB visible; OutA reads done

        // ---- B res GEMM ----
        f32x4 acc2b[4];
#pragma unroll
        for (int nt = 0; nt < 4; nt++) acc2b[nt] = (f32x4){0.f, 0.f, 0.f, 0.f};
        __builtin_amdgcn_s_setprio(1);
#pragma unroll
        for (int s = 0; s < 2; s++) {
#pragma unroll
            for (int nt = 0; nt < 4; nt++) {
                int u = 16 * nt + lo;
                int byte = (u * 128 + s * 64 + hi * 16) ^ ((u & 7) << 4);
                s16x8 bg =
                    __builtin_bit_cast(s16x8, *(const uint4*)(gsb + byte));
                acc2b[nt] = MFMA_F16(ARb[s], bg, acc2b[nt], 0, 0, 0);
            }
        }
        __builtin_amdgcn_s_setprio(0);

        // ---- B act -> OutB (overlay X[0..8K); GsA dead 2 barriers ago) ----
        char* OutB = X;
#pragma unroll
        for (int nt = 0; nt < 4; nt++) {
            int u = 16 * nt + lo;
            float ox = acc2b[nt][0] + rvb[0] + inpb[nt].x;
            float oy = acc2b[nt][1] + rvb[1] + inpb[nt].y;
            float oz = acc2b[nt][2] + rvb[2] + inpb[nt].z;
            float ow = acc2b[nt][3] + rvb[3] + inpb[nt].w;
            int byte = (u * 128 + c0 * 2) ^ ((u & 7) << 4);
            *(uint2*)(OutB + byte) =
                make_uint2(pack_h2(ox, oy), pack_h2(oz, ow));
        }
        // ---- B skip global write ----
        if (tid < 64) {
            float s2 = Sk[tid] + Sk[64 + tid] + Sk[128 + tid] + Sk[192 + tid];
            skip[(size_t)b * T_LEN + t0 + tid] += s2;
        }
        BAR_LGKM();   // OutB visible

        // ---- coalesced copy-out ----
        unsigned short* gH = outH + (size_t)b * T_LEN * NC + (size_t)t0 * 64;
#pragma unroll
        for (int i = 0; i < 2; i++) {
            int u = i * 256 + tid;
            int t = u >> 3, ch = u & 7;
            uint4 v = *(const uint4*)(OutB + t * 128 + ((ch ^ (t & 7)) << 4));
            ((uint4*)gH)[u] = v;
        }
        BAR_LGKM();   // X half safe for stage(j+2)
    }
}

// ------------------------------------------------------------------
extern "C" void kernel_launch(void* const* d_in, const int* in_sizes, int n_in,
                              void* d_out, int out_size, void* d_ws, size_t ws_size,
                              hipStream_t stream) {
    const float* x     = (const float*)d_in[0];
    const float* in_w  = (const float*)d_in[1];
    const float* in_b  = (const float*)d_in[2];
    const float* hid_w = (const float*)d_in[3];
    const float* hid_b = (const float*)d_in[4];
    const float* res_w = (const float*)d_in[5];
    const float* res_b = (const float*)d_in[6];
    const float* mix_w = (const float*)d_in[7];
    const float* mix_b = (const float*)d_in[8];
    float* out = (float*)d_out;

    const size_t actN = (size_t)NB * T_LEN * NC;  // 8388608
    unsigned short* H0 = (unsigned short*)d_ws;
    unsigned short* H1 = H0 + actN;
    unsigned short* Wh = H1 + actN;
    unsigned short* Wr = Wh + (size_t)NL * 128 * 192;
    float* zerobuf = (float*)(Wr + (size_t)NL * 64 * 64);

    prep_kernel<<<512, 256, 0, stream>>>(hid_w, res_w, mix_b, Wh, Wr, out,
                                         zerobuf);

    const unsigned short* srcH = H0;
    unsigned short* dstH = H1;

#define SWAP()                                                                \
    do {                                                                      \
        const unsigned short* tH = srcH;                                      \
        srcH = dstH;                                                          \
        dstH = (unsigned short*)tH;                                           \
    } while (0)
#define LL(D, F, L, i)                                                        \
    layer_kernel<D, F, L><<<512, 256, 0, stream>>>(                           \
        srcH, dstH, Wh + (size_t)(i) * 128 * 192, hid_b + (size_t)(i) * 128,  \
        Wr + (size_t)(i) * 64 * 64, res_b + (size_t)(i) * 64,                 \
        mix_w + (size_t)(i) * 64, out, zerobuf, x, in_w, in_b)
#define LP(DA_, DB_, LA)                                                      \
    pair_kernel<DA_, DB_><<<512, 256, 0, stream>>>(                           \
        srcH, dstH, Wh + (size_t)(LA) * 128 * 192, hid_b + (LA) * 128,        \
        Wr + (size_t)(LA) * 64 * 64, res_b + (LA) * 64, mix_w + (LA) * 64,    \
        Wh + (size_t)(LA + 1) * 128 * 192, hid_b + (LA + 1) * 128,            \
        Wr + (size_t)(LA + 1) * 64 * 64, res_b + (LA + 1) * 64,               \
        mix_w + (LA + 1) * 64, out, zerobuf)

    LL(1, true, false, 0);     SWAP();   // L0 (input conv fused)
    LL(2, false, false, 1);    SWAP();   // L1
    LP(4, 8, 2);               SWAP();   // L2+L3 fused
    LL(16, false, false, 4);   SWAP();
    LL(32, false, false, 5);   SWAP();
    LL(64, false, false, 6);   SWAP();
    LL(128, false, false, 7);  SWAP();
    LL(256, false, false, 8);  SWAP();
    LP(1, 2, 9);               SWAP();   // L9+L10 fused
    LP(4, 8, 11);              SWAP();   // L11+L12 fused
    LL(16, false, false, 13);  SWAP();
    LL(32, false, false, 14);  SWAP();
    LL(64, false, false, 15);  SWAP();
    LL(128, false, false, 16); SWAP();
    LL(256, false, true, 17);
#undef LP
#undef LL
#undef SWAP
}